// Round 2
// baseline (898.321 us; speedup 1.0000x reference)
//
#include <hip/hip_runtime.h>
#include <math.h>

// Mamba forward, MI355X. Round 3:
//  - mfma_gemm_nt: flattened-grid bijective XCD swizzle + M-fastest decomposition
//    (logits GEMM was re-streaming the 49MB emb matrix 8x: FETCH 403MB vs 52MB
//    compulsory; M-fastest keeps one B-panel L2-hot for all 16 M-blocks).
//  - scan_kernel: wave-shuffle prefix scan (2 barriers/scan instead of 16).
#define DM    768
#define DS    16
#define DI    1536
#define DTR   48
#define NB    2
#define NL    1024
#define NBL   (NB*NL)
#define NVOC  32000
#define XDL   128   // padded x_proj output leading dim (80 -> 128)

typedef __attribute__((ext_vector_type(8))) short bf16x8;   // 8 bf16 in 4 VGPRs
typedef __attribute__((ext_vector_type(4))) float floatx4;

static __device__ __forceinline__ float siluf(float x){ return x / (1.0f + expf(-x)); }
static __device__ __forceinline__ float softplusf(float x){ return (x > 20.0f) ? x : log1pf(expf(x)); }
static __device__ __forceinline__ unsigned short f2bf(float f){
    unsigned int u = __float_as_uint(f);
    u += 0x7FFFu + ((u >> 16) & 1u);          // RNE
    return (unsigned short)(u >> 16);
}

#define GLL16(g, l) __builtin_amdgcn_global_load_lds( \
    (const __attribute__((address_space(1))) unsigned int*)(g), \
    (__attribute__((address_space(3))) unsigned int*)(l), 16, 0, 0)

// ---------------- fp32 -> bf16 cast (n multiple of 4) ----------------
__global__ __launch_bounds__(256) void cast_bf16_kernel(const float* __restrict__ in,
        unsigned short* __restrict__ out, int n4){
    int i = blockIdx.x*256 + threadIdx.x;
    if (i >= n4) return;
    float4 v = ((const float4*)in)[i];
    ushort4 o = { f2bf(v.x), f2bf(v.y), f2bf(v.z), f2bf(v.w) };
    ((ushort4*)out)[i] = o;
}

// ---------------- x_proj cast with zero-pad 80 -> 128 rows, both layers ------
// out: [2][128][1536] bf16, in: [2][80][1536] f32
__global__ __launch_bounds__(256) void cast_pad_xproj_kernel(const float* __restrict__ in,
        unsigned short* __restrict__ out){
    int q = blockIdx.x*256 + threadIdx.x;           // quad index
    const int QL = 128*1536/4;                      // quads per layer
    if (q >= 2*QL) return;
    int layer = q / QL, rem = q - layer*QL;
    int row = rem / (1536/4), c4 = rem - row*(1536/4);
    ushort4 o = {0,0,0,0};
    if (row < 80){
        float4 v = ((const float4*)(in + ((size_t)layer*80 + row)*1536))[c4];
        o.x = f2bf(v.x); o.y = f2bf(v.y); o.z = f2bf(v.z); o.w = f2bf(v.w);
    }
    ((ushort4*)out)[q] = o;
}

// ---------------- zero fill (n multiple of 4) ----------------
__global__ __launch_bounds__(256) void zero_f32_kernel(float* __restrict__ p, int n4){
    int i = blockIdx.x*256 + threadIdx.x;
    if (i >= n4) return;
    float4 z = {0.f,0.f,0.f,0.f};
    ((float4*)p)[i] = z;
}

// ---------------- embedding gather ----------------
__global__ __launch_bounds__(256) void embed_kernel(const int* __restrict__ ids,
        const float* __restrict__ emb, float* __restrict__ x){
    int i = blockIdx.x*256 + threadIdx.x;
    if (i >= NBL*DM) return;
    int row = i / DM, c = i - row*DM;
    x[i] = emb[(size_t)ids[row]*DM + c];
}

// ---------------- rmsnorm -> bf16 output ----------------
__global__ __launch_bounds__(256) void rmsnorm_bf16_kernel(const float* __restrict__ x,
        const float* __restrict__ w, unsigned short* __restrict__ h){
    int row = blockIdx.x;
    const float* xr = x + (size_t)row*DM;
    __shared__ float red[256];
    float s = 0.f;
    for (int c = threadIdx.x; c < DM; c += 256){ float v = xr[c]; s += v*v; }
    red[threadIdx.x] = s; __syncthreads();
    for (int o = 128; o > 0; o >>= 1){
        if (threadIdx.x < o) red[threadIdx.x] += red[threadIdx.x + o];
        __syncthreads();
    }
    float r = 1.0f / sqrtf(red[0]*(1.0f/DM) + 1e-5f);
    for (int c = threadIdx.x; c < DM; c += 256) h[(size_t)row*DM + c] = f2bf(xr[c]*r*w[c]);
}

// ---------------- bf16 MFMA GEMM: C[M,N](f32) = A[M,K]bf16 * B[N,K]bf16^T ----
// Requires M%128==0, N%128==0, Kc%32==0. lda=ldb=K, ldc=N.
// m97-style: 128x128 tile, BK=32, global_load_lds width-16 staging,
// 4 waves each computing 64x64 via 4x4 grid of 16x16x32 MFMA.
// Block mapping: flat id -> bijective XCD-chunk swizzle (m204) -> M-fastest
// decomposition. Consecutive blocks on an XCD share one B-panel (L2-hot,
// reused M/128 times) while the whole A matrix stays L2/L3-resident.
// MODE: 0 = store, 1 = read-add-store, 2 = atomicAdd (split-K over blockIdx.z,
//       each z-chunk covers Kc contiguous K; C must be pre-zeroed or hold the
//       accumulation base).
template<int MODE>
__global__ __launch_bounds__(256) void mfma_gemm_nt(const unsigned short* __restrict__ A,
        const unsigned short* __restrict__ B, float* __restrict__ C,
        int M, int N, int K, int Kc){
    __shared__ __align__(16) unsigned short Asm[128*32];
    __shared__ __align__(16) unsigned short Bsm[128*32];
    int tid = threadIdx.x;

    // ---- swizzled block mapping (x-y plane only; z = split-K chunk) ----
    int nwg  = gridDim.x * gridDim.y;
    int orig = blockIdx.y * gridDim.x + blockIdx.x;
    int q = nwg >> 3, r = nwg & 7;
    int xcd = orig & 7;
    int wg  = (xcd < r ? xcd*(q+1) : r*(q+1) + (xcd-r)*q) + (orig >> 3);
    int mb  = wg % gridDim.y;          // M fastest (gridDim.y = M/128)
    int nb  = wg / gridDim.y;
    int m0 = mb * 128, n0 = nb * 128;

    int lane = tid & 63;
    int quad = lane >> 4, l16 = lane & 15;
    int wave = tid >> 6;
    int wm = (wave >> 1) * 64, wn = (wave & 1) * 64;

    floatx4 acc[4][4] = {};

    // staging: lane (tid) loads 16B: row=tid>>2 (0..63), kcol=(tid&3)*8
    int srow = tid >> 2, skcol = (tid & 3) * 8;
    const unsigned short* Ag = A + (size_t)(m0 + srow) * K + skcol;
    const unsigned short* Bg = B + (size_t)(n0 + srow) * K + skcol;
    size_t half = (size_t)64 * K;

    int k0 = blockIdx.z * Kc;
    for (int kt = k0; kt < k0 + Kc; kt += 32){
        // LDS dest: per-lane tid*16B — HW uses wave-uniform base + lane*16,
        // which matches the unpadded [128][32]-ushort row-major layout exactly.
        GLL16(Ag + kt,        &Asm[(size_t)tid*8]);
        GLL16(Ag + kt + half, &Asm[2048 + (size_t)tid*8]);
        GLL16(Bg + kt,        &Bsm[(size_t)tid*8]);
        GLL16(Bg + kt + half, &Bsm[2048 + (size_t)tid*8]);
        __syncthreads();   // compiler drains vmcnt before s_barrier

        bf16x8 af[4], bff[4];
        #pragma unroll
        for (int i = 0; i < 4; i++){
            af[i]  = *(const bf16x8*)&Asm[(wm + i*16 + l16)*32 + quad*8];
            bff[i] = *(const bf16x8*)&Bsm[(wn + i*16 + l16)*32 + quad*8];
        }
        #pragma unroll
        for (int i = 0; i < 4; i++)
            #pragma unroll
            for (int j = 0; j < 4; j++)
                acc[i][j] = __builtin_amdgcn_mfma_f32_16x16x32_bf16(af[i], bff[j], acc[i][j], 0, 0, 0);
        __syncthreads();
    }

    // C/D layout: col = lane&15, row = quad*4 + reg   [m89-verified mapping]
    #pragma unroll
    for (int i = 0; i < 4; i++){
        int gm = m0 + wm + i*16 + quad*4;
        #pragma unroll
        for (int j = 0; j < 4; j++){
            int gn = n0 + wn + j*16 + l16;
            float* cp = C + (size_t)gm*N + gn;
            #pragma unroll
            for (int r = 0; r < 4; r++){
                float v = acc[i][j][r];
                if (MODE == 2){
                    atomicAdd(&cp[(size_t)r*N], v);
                } else {
                    if (MODE == 1) v += cp[(size_t)r*N];
                    cp[(size_t)r*N] = v;
                }
            }
        }
    }
}

// ---------------- fp32 tiled GEMM (small shapes): C = A * Bw^T ----------------
__global__ __launch_bounds__(256) void gemm_nt(const float* __restrict__ A,
        const float* __restrict__ Bw, float* __restrict__ C, const float* __restrict__ bias,
        int M, int N, int K, int lda, int ldb, int ldc, int act, int accum){
    __shared__ float As[16][68];
    __shared__ float Bs[16][68];
    int tid = threadIdx.x;
    int tn = tid & 15, tm = tid >> 4;
    int n0 = blockIdx.x * 64, m0 = blockIdx.y * 64;
    float acc[4][4] = {{0.f}};
    for (int kt = 0; kt < K; kt += 16){
        int gk = kt + tn;
        bool kok = gk < K;
        #pragma unroll
        for (int r = 0; r < 4; r++){
            int m = tm + r*16;
            As[tn][m] = (kok && (m0 + m) < M) ? A[(size_t)(m0+m)*lda + gk] : 0.f;
            Bs[tn][m] = (kok && (n0 + m) < N) ? Bw[(size_t)(n0+m)*ldb + gk] : 0.f;
        }
        __syncthreads();
        #pragma unroll
        for (int kk = 0; kk < 16; kk++){
            float a0 = As[kk][tm*4+0], a1 = As[kk][tm*4+1], a2 = As[kk][tm*4+2], a3 = As[kk][tm*4+3];
            float b0 = Bs[kk][tn*4+0], b1 = Bs[kk][tn*4+1], b2 = Bs[kk][tn*4+2], b3 = Bs[kk][tn*4+3];
            acc[0][0] += a0*b0; acc[0][1] += a0*b1; acc[0][2] += a0*b2; acc[0][3] += a0*b3;
            acc[1][0] += a1*b0; acc[1][1] += a1*b1; acc[1][2] += a1*b2; acc[1][3] += a1*b3;
            acc[2][0] += a2*b0; acc[2][1] += a2*b1; acc[2][2] += a2*b2; acc[2][3] += a2*b3;
            acc[3][0] += a3*b0; acc[3][1] += a3*b1; acc[3][2] += a3*b2; acc[3][3] += a3*b3;
        }
        __syncthreads();
    }
    #pragma unroll
    for (int i = 0; i < 4; i++){
        int gm = m0 + tm*4 + i;
        if (gm >= M) continue;
        #pragma unroll
        for (int j = 0; j < 4; j++){
            int gn = n0 + tn*4 + j;
            if (gn >= N) continue;
            float v = acc[i][j];
            if (bias) v += bias[gn];
            if (act == 1) v = softplusf(v);
            size_t ci = (size_t)gm*ldc + gn;
            if (accum) v += C[ci];
            C[ci] = v;
        }
    }
}

// ---------------- depthwise causal conv (k=4) + bias + silu, f32 + bf16 out --
__global__ __launch_bounds__(256) void conv_silu_kernel(const float* __restrict__ xz,
        const float* __restrict__ cw, const float* __restrict__ cb,
        float* __restrict__ xs, unsigned short* __restrict__ xs_bf){
    int i = blockIdx.x*256 + threadIdx.x;
    if (i >= NBL*DI) return;
    int bl = i / DI, d = i - bl*DI;
    int l = bl & (NL-1);
    float acc = cb[d];
    #pragma unroll
    for (int j = 0; j < 4; j++){
        int off = j - 3;
        if (l + off >= 0) acc += cw[d*4+j] * xz[(size_t)(bl + off)*(2*DI) + d];
    }
    float v = siluf(acc);
    xs[i] = v;
    xs_bf[i] = f2bf(v);
}

// ---------------- transpose: out[C,R] = in[R,C]^T (in has leading dim ldin) --
__global__ __launch_bounds__(256) void transpose_kernel(const float* __restrict__ in,
        float* __restrict__ out, int R, int Ccols, int ldin){
    __shared__ float tile[32][33];
    int c0 = blockIdx.x*32, r0 = blockIdx.y*32;
    int tx = threadIdx.x & 31, ty = threadIdx.x >> 5;
    #pragma unroll
    for (int i = 0; i < 32; i += 8){
        int r = r0 + ty + i, c = c0 + tx;
        tile[ty+i][tx] = (r < R && c < Ccols) ? in[(size_t)r*ldin + c] : 0.f;
    }
    __syncthreads();
    #pragma unroll
    for (int i = 0; i < 32; i += 8){
        int r = r0 + tx, c = c0 + ty + i;
        if (c < Ccols && r < R) out[(size_t)c*R + r] = tile[tx][ty+i];
    }
}

// ---------------- block-wide exclusive prefix sum (256 threads, 4 waves) -----
// Wave-shuffle Hillis-Steele (no barriers) + 4-entry LDS wave combine
// (2 barriers total, vs 16 for the LDS-bounce version).
static __device__ __forceinline__ float block_scan_excl(float v, float* sbuf, float* total){
    int tid  = threadIdx.x;
    int lane = tid & 63, w = tid >> 6;
    float run = v;
    #pragma unroll
    for (int s = 1; s < 64; s <<= 1){
        float t = __shfl_up(run, s, 64);
        if (lane >= s) run += t;
    }
    if (lane == 63) sbuf[w] = run;      // wave totals
    __syncthreads();
    float w0 = sbuf[0], w1 = sbuf[1], w2 = sbuf[2], w3 = sbuf[3];
    __syncthreads();                     // protect sbuf for next call
    float wpre = 0.f;
    if (w > 0) wpre += w0;
    if (w > 1) wpre += w1;
    if (w > 2) wpre += w2;
    *total = w0 + w1 + w2 + w3;
    return wpre + run - v;
}

// ---------------- selective scan (reference numerics) ----------------
// y_t may alias dt_t (per-block row exclusivity; reads precede writes).
__global__ __launch_bounds__(256) void scan_kernel(const float* __restrict__ u_t,
        const float* dt_t, const float* __restrict__ xdbl_t,
        const float* __restrict__ A_log, const float* __restrict__ Dp,
        float* y_t){
    __shared__ float sbuf[8];
    int tid = threadIdx.x;
    int bd = blockIdx.x;
    int b = bd / DI, d = bd - b*DI;
    size_t rowoff = (size_t)d*NBL + b*NL;
    int l0 = tid*4;

    float4 dtv = *(const float4*)(dt_t + rowoff + l0);
    float4 uv  = *(const float4*)(u_t  + rowoff + l0);
    float d4[4] = {dtv.x, dtv.y, dtv.z, dtv.w};
    float u4[4] = {uv.x,  uv.y,  uv.z,  uv.w};
    float pl[4], du[4], yac[4] = {0.f,0.f,0.f,0.f};
    float run = 0.f;
    #pragma unroll
    for (int r = 0; r < 4; r++){ run += d4[r]; pl[r] = run; du[r] = d4[r]*u4[r]; }
    float T;
    float ex = block_scan_excl(run, sbuf, &T);
    #pragma unroll
    for (int r = 0; r < 4; r++) pl[r] += ex;

    for (int n = 0; n < DS; n++){
        float An = -expf(A_log[d*DS + n]);
        float4 Bv4 = *(const float4*)(xdbl_t + (size_t)(DTR+n)*NBL + b*NL + l0);
        float4 Cv4 = *(const float4*)(xdbl_t + (size_t)(DTR+DS+n)*NBL + b*NL + l0);
        float Bv[4] = {Bv4.x, Bv4.y, Bv4.z, Bv4.w};
        float Cv[4] = {Cv4.x, Cv4.y, Cv4.z, Cv4.w};
        float e[4], zl[4];
        float zrun = 0.f;
        #pragma unroll
        for (int r = 0; r < 4; r++){
            e[r] = expf(An * (T - pl[r]));
            zrun += du[r]*Bv[r]*e[r];
            zl[r] = zrun;
        }
        float zt;
        float zex = block_scan_excl(zrun, sbuf, &zt);
        #pragma unroll
        for (int r = 0; r < 4; r++){
            float num = zex + zl[r];
            float xv  = num / (e[r] + 1e-12f);
            yac[r] += xv * Cv[r];
        }
    }
    float Dv = Dp[d];
    float4 yo;
    yo.x = yac[0] + u4[0]*Dv;
    yo.y = yac[1] + u4[1]*Dv;
    yo.z = yac[2] + u4[2]*Dv;
    yo.w = yac[3] + u4[3]*Dv;
    *(float4*)(y_t + rowoff + l0) = yo;
}

// ---------------- transpose y back + gate with silu(res), bf16 output --------
__global__ __launch_bounds__(256) void gate_transpose_kernel(const float* __restrict__ y_t,
        const float* __restrict__ xz, unsigned short* __restrict__ ys){
    __shared__ float tile[32][33];
    int c0 = blockIdx.x*32;   // bl tile
    int r0 = blockIdx.y*32;   // d tile
    int tx = threadIdx.x & 31, ty = threadIdx.x >> 5;
    #pragma unroll
    for (int i = 0; i < 32; i += 8)
        tile[ty+i][tx] = y_t[(size_t)(r0+ty+i)*NBL + (c0+tx)];
    __syncthreads();
    #pragma unroll
    for (int i = 0; i < 32; i += 8){
        int d  = r0 + tx;
        int bl = c0 + ty + i;
        float g = siluf(xz[(size_t)bl*(2*DI) + DI + d]);
        ys[(size_t)bl*DI + d] = f2bf(tile[tx][ty+i] * g);
    }
}

extern "C" void kernel_launch(void* const* d_in, const int* in_sizes, int n_in,
                              void* d_out, int out_size, void* d_ws, size_t ws_size,
                              hipStream_t stream){
    const int*   ids    = (const int*)d_in[0];
    const float* emb    = (const float*)d_in[1];
    const float* W_in   = (const float*)d_in[2];
    const float* convw  = (const float*)d_in[3];
    const float* convb  = (const float*)d_in[4];
    const float* xproj  = (const float*)d_in[5];
    const float* dtw    = (const float*)d_in[6];
    const float* dtbias = (const float*)d_in[7];
    const float* Alog   = (const float*)d_in[8];
    const float* Dpar   = (const float*)d_in[9];
    const float* Wout   = (const float*)d_in[10];
    const float* normw  = (const float*)d_in[11];
    const float* normf  = (const float*)d_in[12];
    float* out = (float*)d_out;

    // ---- workspace layout ----
    float* ws    = (float*)d_ws;
    float* x     = ws;                              // NBL*DM f32
    float* xz    = x     + (size_t)NBL*DM;          // NBL*2*DI f32
    float* xs    = xz    + (size_t)NBL*2*DI;        // NBL*DI f32
    float* xdbl  = xs    + (size_t)NBL*DI;          // NBL*XDL f32 (padded, 80 valid)
    float* xdblt = xdbl  + (size_t)NBL*XDL;         // 80*NBL f32
    float* dtb   = xdblt + (size_t)NBL*80;          // NBL*DI f32 (later: ys_bf as ushort)
    float* dtt   = dtb   + (size_t)NBL*DI;          // DI*NBL f32 (scan writes y here too)
    float* ut    = dtt   + (size_t)NBL*DI;          // DI*NBL f32
    unsigned short* h_bf   = (unsigned short*)(ut + (size_t)NBL*DI);   // NBL*DM
    unsigned short* emb_bf = h_bf    + (size_t)NBL*DM;                 // NVOC*DM
    unsigned short* win_bf = emb_bf  + (size_t)NVOC*DM;                // 2*2*DI*DM
    unsigned short* wout_bf= win_bf  + (size_t)2*2*DI*DM;              // 2*DM*DI
    unsigned short* xs_bf  = wout_bf + (size_t)2*DM*DI;                // NBL*DI
    unsigned short* xprojp = xs_bf   + (size_t)NBL*DI;                 // 2*128*1536 (zero-padded)
    unsigned short* ys_bf  = (unsigned short*)dtb;
    float* yt = dtt;   // alias: scan writes y over dt (row-exclusive, safe)

    // ---- weight / emb casts (every call; ws is re-poisoned by harness) ----
    cast_bf16_kernel<<<(NVOC*DM/4 + 255)/256, 256, 0, stream>>>(emb, emb_bf, NVOC*DM/4);
    cast_bf16_kernel<<<(2*2*DI*DM/4 + 255)/256, 256, 0, stream>>>(W_in, win_bf, 2*2*DI*DM/4);
    cast_bf16_kernel<<<(2*DM*DI/4 + 255)/256, 256, 0, stream>>>(Wout, wout_bf, 2*DM*DI/4);
    cast_pad_xproj_kernel<<<(2*128*1536/4 + 255)/256, 256, 0, stream>>>(xproj, xprojp);

    embed_kernel<<<(NBL*DM + 255)/256, 256, 0, stream>>>(ids, emb, x);

    for (int i = 0; i < 2; i++){
        rmsnorm_bf16_kernel<<<NBL, 256, 0, stream>>>(x, normw + i*DM, h_bf);
        // xz = h @ W_in^T   (2048 x 3072, K=768) — bf16 MFMA
        mfma_gemm_nt<0><<<dim3(3072/128, NBL/128, 1), 256, 0, stream>>>(
                h_bf, win_bf + (size_t)i*2*DI*DM, xz, NBL, 2*DI, DM, DM);
        conv_silu_kernel<<<(NBL*DI + 255)/256, 256, 0, stream>>>(xz, convw + i*DI*4, convb + i*DI, xs, xs_bf);
        // xdbl = xs @ x_proj^T   (2048 x 80->128pad, K=1536) — bf16 MFMA split-K
        zero_f32_kernel<<<(NBL*XDL/4 + 255)/256, 256, 0, stream>>>(xdbl, NBL*XDL/4);
        mfma_gemm_nt<2><<<dim3(1, NBL/128, 8), 256, 0, stream>>>(
                xs_bf, xprojp + (size_t)i*128*DI, xdbl, NBL, XDL, DI, DI/8);
        // dt = softplus(xdbl[:, :48] @ dt_proj^T + bias)   (2048 x 1536, K=48) — fp32
        gemm_nt<<<dim3(24,32), 256, 0, stream>>>(xdbl, dtw + (size_t)i*DI*DTR, dtb, dtbias + i*DI,
                NBL, DI, DTR, XDL, DTR, DI, 1, 0);
        transpose_kernel<<<dim3(3,64),  256, 0, stream>>>(xdbl, xdblt, NBL, 80, XDL);
        transpose_kernel<<<dim3(48,64), 256, 0, stream>>>(dtb,  dtt,   NBL, DI, DI);
        transpose_kernel<<<dim3(48,64), 256, 0, stream>>>(xs,   ut,    NBL, DI, DI);
        scan_kernel<<<NB*DI, 256, 0, stream>>>(ut, dtt, xdblt,
                Alog + (size_t)i*DI*DS, Dpar + i*DI, yt);
        gate_transpose_kernel<<<dim3(64,48), 256, 0, stream>>>(yt, xz, ys_bf);
        // x += ys @ W_out^T   (2048 x 768, K=1536) — bf16 MFMA split-K, atomic
        // accumulate directly into the residual x (same result as read-add-store)
        mfma_gemm_nt<2><<<dim3(DM/128, NBL/128, 2), 256, 0, stream>>>(
                ys_bf, wout_bf + (size_t)i*DM*DI, x, NBL, DM, DI, DI/2);
    }

    rmsnorm_bf16_kernel<<<NBL, 256, 0, stream>>>(x, normf, h_bf);
    // logits = h @ emb^T   (2048 x 32000, K=768) — bf16 MFMA
    mfma_gemm_nt<0><<<dim3(NVOC/128, NBL/128, 1), 256, 0, stream>>>(
            h_bf, emb_bf, out, NBL, NVOC, DM, DM);
}

// Round 3
// 888.807 us; speedup vs baseline: 1.0107x; 1.0107x over previous
//
#include <hip/hip_runtime.h>
#include <math.h>

// Mamba forward, MI355X. Round 4:
//  - mfma_gemm_nt: BK 32->64 (halves barrier/vmcnt-drain events per K; the
//    logits GEMM was sync-overhead-bound at 22% MfmaUtil / 25% HBM) with
//    XOR-swizzled LDS (read-side chunk ^= row&7, inverse pre-applied to the
//    global source so the linear global_load_lds dest stays valid; kills the
//    12.3M 8-way bank conflicts).
//  - scan_kernel: one wave per (b,d) row, zero barriers (pure shfl scans).
//  - fused double-transpose for dt/xs.
#define DM    768
#define DS    16
#define DI    1536
#define DTR   48
#define NB    2
#define NL    1024
#define NBL   (NB*NL)
#define NVOC  32000
#define XDL   128   // padded x_proj output leading dim (80 -> 128)

typedef __attribute__((ext_vector_type(8))) short bf16x8;   // 8 bf16 in 4 VGPRs
typedef __attribute__((ext_vector_type(4))) float floatx4;

static __device__ __forceinline__ float siluf(float x){ return x / (1.0f + expf(-x)); }
static __device__ __forceinline__ float softplusf(float x){ return (x > 20.0f) ? x : log1pf(expf(x)); }
static __device__ __forceinline__ unsigned short f2bf(float f){
    unsigned int u = __float_as_uint(f);
    u += 0x7FFFu + ((u >> 16) & 1u);          // RNE
    return (unsigned short)(u >> 16);
}

#define GLL16(g, l) __builtin_amdgcn_global_load_lds( \
    (const __attribute__((address_space(1))) unsigned int*)(g), \
    (__attribute__((address_space(3))) unsigned int*)(l), 16, 0, 0)

// ---------------- fp32 -> bf16 cast (n multiple of 4) ----------------
__global__ __launch_bounds__(256) void cast_bf16_kernel(const float* __restrict__ in,
        unsigned short* __restrict__ out, int n4){
    int i = blockIdx.x*256 + threadIdx.x;
    if (i >= n4) return;
    float4 v = ((const float4*)in)[i];
    ushort4 o = { f2bf(v.x), f2bf(v.y), f2bf(v.z), f2bf(v.w) };
    ((ushort4*)out)[i] = o;
}

// ---------------- x_proj cast with zero-pad 80 -> 128 rows, both layers ------
// out: [2][128][1536] bf16, in: [2][80][1536] f32
__global__ __launch_bounds__(256) void cast_pad_xproj_kernel(const float* __restrict__ in,
        unsigned short* __restrict__ out){
    int q = blockIdx.x*256 + threadIdx.x;           // quad index
    const int QL = 128*1536/4;                      // quads per layer
    if (q >= 2*QL) return;
    int layer = q / QL, rem = q - layer*QL;
    int row = rem / (1536/4), c4 = rem - row*(1536/4);
    ushort4 o = {0,0,0,0};
    if (row < 80){
        float4 v = ((const float4*)(in + ((size_t)layer*80 + row)*1536))[c4];
        o.x = f2bf(v.x); o.y = f2bf(v.y); o.z = f2bf(v.z); o.w = f2bf(v.w);
    }
    ((ushort4*)out)[q] = o;
}

// ---------------- zero fill (n multiple of 4) ----------------
__global__ __launch_bounds__(256) void zero_f32_kernel(float* __restrict__ p, int n4){
    int i = blockIdx.x*256 + threadIdx.x;
    if (i >= n4) return;
    float4 z = {0.f,0.f,0.f,0.f};
    ((float4*)p)[i] = z;
}

// ---------------- embedding gather ----------------
__global__ __launch_bounds__(256) void embed_kernel(const int* __restrict__ ids,
        const float* __restrict__ emb, float* __restrict__ x){
    int i = blockIdx.x*256 + threadIdx.x;
    if (i >= NBL*DM) return;
    int row = i / DM, c = i - row*DM;
    x[i] = emb[(size_t)ids[row]*DM + c];
}

// ---------------- rmsnorm -> bf16 output ----------------
__global__ __launch_bounds__(256) void rmsnorm_bf16_kernel(const float* __restrict__ x,
        const float* __restrict__ w, unsigned short* __restrict__ h){
    int row = blockIdx.x;
    const float* xr = x + (size_t)row*DM;
    __shared__ float red[256];
    float s = 0.f;
    for (int c = threadIdx.x; c < DM; c += 256){ float v = xr[c]; s += v*v; }
    red[threadIdx.x] = s; __syncthreads();
    for (int o = 128; o > 0; o >>= 1){
        if (threadIdx.x < o) red[threadIdx.x] += red[threadIdx.x + o];
        __syncthreads();
    }
    float r = 1.0f / sqrtf(red[0]*(1.0f/DM) + 1e-5f);
    for (int c = threadIdx.x; c < DM; c += 256) h[(size_t)row*DM + c] = f2bf(xr[c]*r*w[c]);
}

// ---------------- bf16 MFMA GEMM: C[M,N](f32) = A[M,K]bf16 * B[N,K]bf16^T ----
// Requires M%128==0, N%128==0, Kc%64==0. lda=ldb=K, ldc=N.
// 128x128 tile, BK=64, global_load_lds width-16 staging into XOR-swizzled LDS:
// LDS chunk (row, c) holds global 16B-chunk (row, c ^ (row&7)); the inverse is
// applied to the per-lane GLOBAL source address (staging dest stays linear,
// which global_load_lds requires), readers XOR the chunk index. This makes
// the stride-128B fragment reads conflict-free (was 8-way at BK=32).
// Block mapping: flat id -> bijective XCD-chunk swizzle (m204) -> M-fastest.
// MODE: 0 = store, 1 = read-add-store, 2 = atomicAdd (split-K over blockIdx.z).
template<int MODE>
__global__ __launch_bounds__(256) void mfma_gemm_nt(const unsigned short* __restrict__ A,
        const unsigned short* __restrict__ B, float* __restrict__ C,
        int M, int N, int K, int Kc){
    __shared__ __align__(16) unsigned short Asm[128*64];
    __shared__ __align__(16) unsigned short Bsm[128*64];
    int tid = threadIdx.x;

    // ---- swizzled block mapping (x-y plane only; z = split-K chunk) ----
    int nwg  = gridDim.x * gridDim.y;
    int orig = blockIdx.y * gridDim.x + blockIdx.x;
    int q = nwg >> 3, r = nwg & 7;
    int xcd = orig & 7;
    int wg  = (xcd < r ? xcd*(q+1) : r*(q+1) + (xcd-r)*q) + (orig >> 3);
    int mb  = wg % gridDim.y;          // M fastest (gridDim.y = M/128)
    int nb  = wg / gridDim.y;
    int m0 = mb * 128, n0 = nb * 128;

    int lane = tid & 63;
    int quad = lane >> 4, l16 = lane & 15;
    int wave = tid >> 6;
    int wm = (wave >> 1) * 64, wn = (wave & 1) * 64;

    floatx4 acc[4][4] = {};

    // staging: round qr (0..3), chunk n = qr*256+tid; row = n>>3 = qr*32+(tid>>3),
    // dest chunk c = tid&7; source chunk = c ^ (row&7) = (tid&7)^((tid>>3)&7)
    // -> per-thread-constant source column offset.
    int srow = tid >> 3;                                   // 0..31
    int csrc = ((tid & 7) ^ ((tid >> 3) & 7)) * 8;         // ushort offset
    const unsigned short* Ag = A + (size_t)(m0 + srow) * K + csrc;
    const unsigned short* Bg = B + (size_t)(n0 + srow) * K + csrc;

    int k0 = blockIdx.z * Kc;
    for (int kt = k0; kt < k0 + Kc; kt += 64){
        #pragma unroll
        for (int qr = 0; qr < 4; qr++){
            GLL16(Ag + (size_t)qr*32*K + kt, &Asm[((size_t)qr*256 + tid)*8]);
            GLL16(Bg + (size_t)qr*32*K + kt, &Bsm[((size_t)qr*256 + tid)*8]);
        }
        __syncthreads();   // compiler drains vmcnt before s_barrier

        #pragma unroll
        for (int ks = 0; ks < 2; ks++){
            bf16x8 af[4], bff[4];
            #pragma unroll
            for (int i = 0; i < 4; i++){
                int ar = wm + i*16 + l16;
                af[i]  = *(const bf16x8*)&Asm[ar*64 + ((ks*4 + quad) ^ (ar & 7))*8];
                int br = wn + i*16 + l16;
                bff[i] = *(const bf16x8*)&Bsm[br*64 + ((ks*4 + quad) ^ (br & 7))*8];
            }
            #pragma unroll
            for (int i = 0; i < 4; i++)
                #pragma unroll
                for (int j = 0; j < 4; j++)
                    acc[i][j] = __builtin_amdgcn_mfma_f32_16x16x32_bf16(af[i], bff[j], acc[i][j], 0, 0, 0);
        }
        __syncthreads();
    }

    // C/D layout: col = lane&15, row = quad*4 + reg   [m89-verified mapping]
    #pragma unroll
    for (int i = 0; i < 4; i++){
        int gm = m0 + wm + i*16 + quad*4;
        #pragma unroll
        for (int j = 0; j < 4; j++){
            int gn = n0 + wn + j*16 + l16;
            float* cp = C + (size_t)gm*N + gn;
            #pragma unroll
            for (int rr = 0; rr < 4; rr++){
                float v = acc[i][j][rr];
                if (MODE == 2){
                    atomicAdd(&cp[(size_t)rr*N], v);
                } else {
                    if (MODE == 1) v += cp[(size_t)rr*N];
                    cp[(size_t)rr*N] = v;
                }
            }
        }
    }
}

// ---------------- fp32 tiled GEMM (small shapes): C = A * Bw^T ----------------
__global__ __launch_bounds__(256) void gemm_nt(const float* __restrict__ A,
        const float* __restrict__ Bw, float* __restrict__ C, const float* __restrict__ bias,
        int M, int N, int K, int lda, int ldb, int ldc, int act, int accum){
    __shared__ float As[16][68];
    __shared__ float Bs[16][68];
    int tid = threadIdx.x;
    int tn = tid & 15, tm = tid >> 4;
    int n0 = blockIdx.x * 64, m0 = blockIdx.y * 64;
    float acc[4][4] = {{0.f}};
    for (int kt = 0; kt < K; kt += 16){
        int gk = kt + tn;
        bool kok = gk < K;
        #pragma unroll
        for (int r = 0; r < 4; r++){
            int m = tm + r*16;
            As[tn][m] = (kok && (m0 + m) < M) ? A[(size_t)(m0+m)*lda + gk] : 0.f;
            Bs[tn][m] = (kok && (n0 + m) < N) ? Bw[(size_t)(n0+m)*ldb + gk] : 0.f;
        }
        __syncthreads();
        #pragma unroll
        for (int kk = 0; kk < 16; kk++){
            float a0 = As[kk][tm*4+0], a1 = As[kk][tm*4+1], a2 = As[kk][tm*4+2], a3 = As[kk][tm*4+3];
            float b0 = Bs[kk][tn*4+0], b1 = Bs[kk][tn*4+1], b2 = Bs[kk][tn*4+2], b3 = Bs[kk][tn*4+3];
            acc[0][0] += a0*b0; acc[0][1] += a0*b1; acc[0][2] += a0*b2; acc[0][3] += a0*b3;
            acc[1][0] += a1*b0; acc[1][1] += a1*b1; acc[1][2] += a1*b2; acc[1][3] += a1*b3;
            acc[2][0] += a2*b0; acc[2][1] += a2*b1; acc[2][2] += a2*b2; acc[2][3] += a2*b3;
            acc[3][0] += a3*b0; acc[3][1] += a3*b1; acc[3][2] += a3*b2; acc[3][3] += a3*b3;
        }
        __syncthreads();
    }
    #pragma unroll
    for (int i = 0; i < 4; i++){
        int gm = m0 + tm*4 + i;
        if (gm >= M) continue;
        #pragma unroll
        for (int j = 0; j < 4; j++){
            int gn = n0 + tn*4 + j;
            if (gn >= N) continue;
            float v = acc[i][j];
            if (bias) v += bias[gn];
            if (act == 1) v = softplusf(v);
            size_t ci = (size_t)gm*ldc + gn;
            if (accum) v += C[ci];
            C[ci] = v;
        }
    }
}

// ---------------- depthwise causal conv (k=4) + bias + silu, f32 + bf16 out --
__global__ __launch_bounds__(256) void conv_silu_kernel(const float* __restrict__ xz,
        const float* __restrict__ cw, const float* __restrict__ cb,
        float* __restrict__ xs, unsigned short* __restrict__ xs_bf){
    int i = blockIdx.x*256 + threadIdx.x;
    if (i >= NBL*DI) return;
    int bl = i / DI, d = i - bl*DI;
    int l = bl & (NL-1);
    float acc = cb[d];
    #pragma unroll
    for (int j = 0; j < 4; j++){
        int off = j - 3;
        if (l + off >= 0) acc += cw[d*4+j] * xz[(size_t)(bl + off)*(2*DI) + d];
    }
    float v = siluf(acc);
    xs[i] = v;
    xs_bf[i] = f2bf(v);
}

// ---------------- transpose: out[C,R] = in[R,C]^T (in has leading dim ldin) --
__global__ __launch_bounds__(256) void transpose_kernel(const float* __restrict__ in,
        float* __restrict__ out, int R, int Ccols, int ldin){
    __shared__ float tile[32][33];
    int c0 = blockIdx.x*32, r0 = blockIdx.y*32;
    int tx = threadIdx.x & 31, ty = threadIdx.x >> 5;
    #pragma unroll
    for (int i = 0; i < 32; i += 8){
        int r = r0 + ty + i, c = c0 + tx;
        tile[ty+i][tx] = (r < R && c < Ccols) ? in[(size_t)r*ldin + c] : 0.f;
    }
    __syncthreads();
    #pragma unroll
    for (int i = 0; i < 32; i += 8){
        int r = r0 + tx, c = c0 + ty + i;
        if (c < Ccols && r < R) out[(size_t)c*R + r] = tile[tx][ty+i];
    }
}

// ---------------- fused double transpose: NBL x DI -> DI x NBL, two arrays ---
__global__ __launch_bounds__(256) void transpose2_kernel(const float* __restrict__ in1,
        float* __restrict__ out1, const float* __restrict__ in2, float* __restrict__ out2){
    __shared__ float tile[32][33];
    int c0 = blockIdx.x*32, r0 = blockIdx.y*32;   // c over DI, r over NBL
    int tx = threadIdx.x & 31, ty = threadIdx.x >> 5;
    #pragma unroll
    for (int i = 0; i < 32; i += 8)
        tile[ty+i][tx] = in1[(size_t)(r0+ty+i)*DI + (c0+tx)];
    __syncthreads();
    #pragma unroll
    for (int i = 0; i < 32; i += 8)
        out1[(size_t)(c0+ty+i)*NBL + (r0+tx)] = tile[tx][ty+i];
    __syncthreads();
    #pragma unroll
    for (int i = 0; i < 32; i += 8)
        tile[ty+i][tx] = in2[(size_t)(r0+ty+i)*DI + (c0+tx)];
    __syncthreads();
    #pragma unroll
    for (int i = 0; i < 32; i += 8)
        out2[(size_t)(c0+ty+i)*NBL + (r0+tx)] = tile[tx][ty+i];
}

// ---------------- wave-inclusive prefix scan (64 lanes, no barriers) ---------
static __device__ __forceinline__ float wave_incl_scan(float v, int lane){
    #pragma unroll
    for (int s = 1; s < 64; s <<= 1){
        float t = __shfl_up(v, s, 64);
        if (lane >= s) v += t;
    }
    return v;
}

// ---------------- selective scan (reference numerics) ----------------
// One WAVE per (b,d) row: 16 elements/lane, pure shuffle scans, zero barriers.
// y_t may alias dt_t (per-wave row exclusivity; reads precede writes).
__global__ __launch_bounds__(256) void scan_kernel(const float* __restrict__ u_t,
        const float* dt_t, const float* __restrict__ xdbl_t,
        const float* __restrict__ A_log, const float* __restrict__ Dp,
        float* y_t){
    int tid = threadIdx.x, lane = tid & 63, w = tid >> 6;
    int bd = blockIdx.x*4 + w;
    int b = bd / DI, d = bd - b*DI;
    size_t rowoff = (size_t)d*NBL + b*NL;
    int l0 = lane*16;

    float d16[16], u16[16];
    #pragma unroll
    for (int q = 0; q < 4; q++){
        float4 v = ((const float4*)(dt_t + rowoff + l0))[q];
        d16[q*4+0]=v.x; d16[q*4+1]=v.y; d16[q*4+2]=v.z; d16[q*4+3]=v.w;
        float4 u = ((const float4*)(u_t + rowoff + l0))[q];
        u16[q*4+0]=u.x; u16[q*4+1]=u.y; u16[q*4+2]=u.z; u16[q*4+3]=u.w;
    }
    float pl[16], yac[16];
    float run = 0.f;
    #pragma unroll
    for (int r = 0; r < 16; r++){ run += d16[r]; pl[r] = run; yac[r] = 0.f; }
    float inc = wave_incl_scan(run, lane);
    float ex  = inc - run;
    float T   = __shfl(inc, 63, 64);
    #pragma unroll
    for (int r = 0; r < 16; r++) pl[r] += ex;

    for (int n = 0; n < DS; n++){
        float An = -expf(A_log[d*DS + n]);
        float Bv[16], Cv[16];
        #pragma unroll
        for (int q = 0; q < 4; q++){
            float4 bv = ((const float4*)(xdbl_t + (size_t)(DTR+n)*NBL + b*NL + l0))[q];
            Bv[q*4+0]=bv.x; Bv[q*4+1]=bv.y; Bv[q*4+2]=bv.z; Bv[q*4+3]=bv.w;
            float4 cv = ((const float4*)(xdbl_t + (size_t)(DTR+DS+n)*NBL + b*NL + l0))[q];
            Cv[q*4+0]=cv.x; Cv[q*4+1]=cv.y; Cv[q*4+2]=cv.z; Cv[q*4+3]=cv.w;
        }
        float e[16], zl[16];
        float zrun = 0.f;
        #pragma unroll
        for (int r = 0; r < 16; r++){
            e[r] = expf(An * (T - pl[r]));
            zrun += d16[r]*u16[r]*Bv[r]*e[r];
            zl[r] = zrun;
        }
        float zinc = wave_incl_scan(zrun, lane);
        float zex  = zinc - zrun;
        #pragma unroll
        for (int r = 0; r < 16; r++){
            float num = zex + zl[r];
            yac[r] += num / (e[r] + 1e-12f) * Cv[r];
        }
    }
    float Dv = Dp[d];
    #pragma unroll
    for (int q = 0; q < 4; q++){
        float4 yo;
        yo.x = yac[q*4+0] + u16[q*4+0]*Dv;
        yo.y = yac[q*4+1] + u16[q*4+1]*Dv;
        yo.z = yac[q*4+2] + u16[q*4+2]*Dv;
        yo.w = yac[q*4+3] + u16[q*4+3]*Dv;
        ((float4*)(y_t + rowoff + l0))[q] = yo;
    }
}

// ---------------- transpose y back + gate with silu(res), bf16 output --------
__global__ __launch_bounds__(256) void gate_transpose_kernel(const float* __restrict__ y_t,
        const float* __restrict__ xz, unsigned short* __restrict__ ys){
    __shared__ float tile[32][33];
    int c0 = blockIdx.x*32;   // bl tile
    int r0 = blockIdx.y*32;   // d tile
    int tx = threadIdx.x & 31, ty = threadIdx.x >> 5;
    #pragma unroll
    for (int i = 0; i < 32; i += 8)
        tile[ty+i][tx] = y_t[(size_t)(r0+ty+i)*NBL + (c0+tx)];
    __syncthreads();
    #pragma unroll
    for (int i = 0; i < 32; i += 8){
        int d  = r0 + tx;
        int bl = c0 + ty + i;
        float g = siluf(xz[(size_t)bl*(2*DI) + DI + d]);
        ys[(size_t)bl*DI + d] = f2bf(tile[tx][ty+i] * g);
    }
}

extern "C" void kernel_launch(void* const* d_in, const int* in_sizes, int n_in,
                              void* d_out, int out_size, void* d_ws, size_t ws_size,
                              hipStream_t stream){
    const int*   ids    = (const int*)d_in[0];
    const float* emb    = (const float*)d_in[1];
    const float* W_in   = (const float*)d_in[2];
    const float* convw  = (const float*)d_in[3];
    const float* convb  = (const float*)d_in[4];
    const float* xproj  = (const float*)d_in[5];
    const float* dtw    = (const float*)d_in[6];
    const float* dtbias = (const float*)d_in[7];
    const float* Alog   = (const float*)d_in[8];
    const float* Dpar   = (const float*)d_in[9];
    const float* Wout   = (const float*)d_in[10];
    const float* normw  = (const float*)d_in[11];
    const float* normf  = (const float*)d_in[12];
    float* out = (float*)d_out;

    // ---- workspace layout ----
    float* ws    = (float*)d_ws;
    float* x     = ws;                              // NBL*DM f32
    float* xz    = x     + (size_t)NBL*DM;          // NBL*2*DI f32
    float* xs    = xz    + (size_t)NBL*2*DI;        // NBL*DI f32
    float* xdbl  = xs    + (size_t)NBL*DI;          // NBL*XDL f32 (padded, 80 valid)
    float* xdblt = xdbl  + (size_t)NBL*XDL;         // 80*NBL f32
    float* dtb   = xdblt + (size_t)NBL*80;          // NBL*DI f32 (later: ys_bf as ushort)
    float* dtt   = dtb   + (size_t)NBL*DI;          // DI*NBL f32 (scan writes y here too)
    float* ut    = dtt   + (size_t)NBL*DI;          // DI*NBL f32
    unsigned short* h_bf   = (unsigned short*)(ut + (size_t)NBL*DI);   // NBL*DM
    unsigned short* emb_bf = h_bf    + (size_t)NBL*DM;                 // NVOC*DM
    unsigned short* win_bf = emb_bf  + (size_t)NVOC*DM;                // 2*2*DI*DM
    unsigned short* wout_bf= win_bf  + (size_t)2*2*DI*DM;              // 2*DM*DI
    unsigned short* xs_bf  = wout_bf + (size_t)2*DM*DI;                // NBL*DI
    unsigned short* xprojp = xs_bf   + (size_t)NBL*DI;                 // 2*128*1536 (zero-padded)
    unsigned short* ys_bf  = (unsigned short*)dtb;
    float* yt = dtt;   // alias: scan writes y over dt (row-exclusive, safe)

    // ---- weight / emb casts (every call; ws is re-poisoned by harness) ----
    cast_bf16_kernel<<<(NVOC*DM/4 + 255)/256, 256, 0, stream>>>(emb, emb_bf, NVOC*DM/4);
    cast_bf16_kernel<<<(2*2*DI*DM/4 + 255)/256, 256, 0, stream>>>(W_in, win_bf, 2*2*DI*DM/4);
    cast_bf16_kernel<<<(2*DM*DI/4 + 255)/256, 256, 0, stream>>>(Wout, wout_bf, 2*DM*DI/4);
    cast_pad_xproj_kernel<<<(2*128*1536/4 + 255)/256, 256, 0, stream>>>(xproj, xprojp);

    embed_kernel<<<(NBL*DM + 255)/256, 256, 0, stream>>>(ids, emb, x);

    for (int i = 0; i < 2; i++){
        rmsnorm_bf16_kernel<<<NBL, 256, 0, stream>>>(x, normw + i*DM, h_bf);
        // xz = h @ W_in^T   (2048 x 3072, K=768) — bf16 MFMA
        mfma_gemm_nt<0><<<dim3(3072/128, NBL/128, 1), 256, 0, stream>>>(
                h_bf, win_bf + (size_t)i*2*DI*DM, xz, NBL, 2*DI, DM, DM);
        conv_silu_kernel<<<(NBL*DI + 255)/256, 256, 0, stream>>>(xz, convw + i*DI*4, convb + i*DI, xs, xs_bf);
        // xdbl = xs @ x_proj^T   (2048 x 80->128pad, K=1536) — bf16 MFMA split-K
        zero_f32_kernel<<<(NBL*XDL/4 + 255)/256, 256, 0, stream>>>(xdbl, NBL*XDL/4);
        mfma_gemm_nt<2><<<dim3(1, NBL/128, 8), 256, 0, stream>>>(
                xs_bf, xprojp + (size_t)i*128*DI, xdbl, NBL, XDL, DI, DI/8);
        // dt = softplus(xdbl[:, :48] @ dt_proj^T + bias)   (2048 x 1536, K=48) — fp32
        gemm_nt<<<dim3(24,32), 256, 0, stream>>>(xdbl, dtw + (size_t)i*DI*DTR, dtb, dtbias + i*DI,
                NBL, DI, DTR, XDL, DTR, DI, 1, 0);
        transpose_kernel<<<dim3(3,64),  256, 0, stream>>>(xdbl, xdblt, NBL, 80, XDL);
        transpose2_kernel<<<dim3(48,64), 256, 0, stream>>>(dtb, dtt, xs, ut);
        scan_kernel<<<NB*DI/4, 256, 0, stream>>>(ut, dtt, xdblt,
                Alog + (size_t)i*DI*DS, Dpar + i*DI, yt);
        gate_transpose_kernel<<<dim3(64,48), 256, 0, stream>>>(yt, xz, ys_bf);
        // x += ys @ W_out^T   (2048 x 768, K=1536) — bf16 MFMA split-K, atomic
        mfma_gemm_nt<2><<<dim3(DM/128, NBL/128, 2), 256, 0, stream>>>(
                ys_bf, wout_bf + (size_t)i*DM*DI, x, NBL, DM, DI, DI/2);
    }

    rmsnorm_bf16_kernel<<<NBL, 256, 0, stream>>>(x, normf, h_bf);
    // logits = h @ emb^T   (2048 x 32000, K=768) — bf16 MFMA
    mfma_gemm_nt<0><<<dim3(NVOC/128, NBL/128, 1), 256, 0, stream>>>(
            h_bf, emb_bf, out, NBL, NVOC, DM, DM);
}

// Round 4
// 877.630 us; speedup vs baseline: 1.0236x; 1.0127x over previous
//
#include <hip/hip_runtime.h>
#include <math.h>

// Mamba forward, MI355X. Round 5:
//  - mfma_gemm_nt: double-buffered LDS prefetch pipeline (T3-minimal): issue
//    next tile's global_load_lds BEFORE computing current tile; single
//    __syncthreads per K-step. Round-4 counters showed stall-bound (MfmaUtil
//    20%, VALU 27%, conflicts 0, occupancy 1.6 blk/CU) — the per-step
//    vmcnt(0)-drain-before-compute was the critical path.
//  - rmsnorm: wave-shuffle reduction (1 barrier instead of 8).
#define DM    768
#define DS    16
#define DI    1536
#define DTR   48
#define NB    2
#define NL    1024
#define NBL   (NB*NL)
#define NVOC  32000
#define XDL   128   // padded x_proj output leading dim (80 -> 128)

typedef __attribute__((ext_vector_type(8))) short bf16x8;   // 8 bf16 in 4 VGPRs
typedef __attribute__((ext_vector_type(4))) float floatx4;

static __device__ __forceinline__ float siluf(float x){ return x / (1.0f + expf(-x)); }
static __device__ __forceinline__ float softplusf(float x){ return (x > 20.0f) ? x : log1pf(expf(x)); }
static __device__ __forceinline__ unsigned short f2bf(float f){
    unsigned int u = __float_as_uint(f);
    u += 0x7FFFu + ((u >> 16) & 1u);          // RNE
    return (unsigned short)(u >> 16);
}

#define GLL16(g, l) __builtin_amdgcn_global_load_lds( \
    (const __attribute__((address_space(1))) unsigned int*)(g), \
    (__attribute__((address_space(3))) unsigned int*)(l), 16, 0, 0)

// ---------------- fp32 -> bf16 cast (n multiple of 4) ----------------
__global__ __launch_bounds__(256) void cast_bf16_kernel(const float* __restrict__ in,
        unsigned short* __restrict__ out, int n4){
    int i = blockIdx.x*256 + threadIdx.x;
    if (i >= n4) return;
    float4 v = ((const float4*)in)[i];
    ushort4 o = { f2bf(v.x), f2bf(v.y), f2bf(v.z), f2bf(v.w) };
    ((ushort4*)out)[i] = o;
}

// ---------------- x_proj cast with zero-pad 80 -> 128 rows, both layers ------
// out: [2][128][1536] bf16, in: [2][80][1536] f32
__global__ __launch_bounds__(256) void cast_pad_xproj_kernel(const float* __restrict__ in,
        unsigned short* __restrict__ out){
    int q = blockIdx.x*256 + threadIdx.x;           // quad index
    const int QL = 128*1536/4;                      // quads per layer
    if (q >= 2*QL) return;
    int layer = q / QL, rem = q - layer*QL;
    int row = rem / (1536/4), c4 = rem - row*(1536/4);
    ushort4 o = {0,0,0,0};
    if (row < 80){
        float4 v = ((const float4*)(in + ((size_t)layer*80 + row)*1536))[c4];
        o.x = f2bf(v.x); o.y = f2bf(v.y); o.z = f2bf(v.z); o.w = f2bf(v.w);
    }
    ((ushort4*)out)[q] = o;
}

// ---------------- zero fill (n multiple of 4) ----------------
__global__ __launch_bounds__(256) void zero_f32_kernel(float* __restrict__ p, int n4){
    int i = blockIdx.x*256 + threadIdx.x;
    if (i >= n4) return;
    float4 z = {0.f,0.f,0.f,0.f};
    ((float4*)p)[i] = z;
}

// ---------------- embedding gather ----------------
__global__ __launch_bounds__(256) void embed_kernel(const int* __restrict__ ids,
        const float* __restrict__ emb, float* __restrict__ x){
    int i = blockIdx.x*256 + threadIdx.x;
    if (i >= NBL*DM) return;
    int row = i / DM, c = i - row*DM;
    x[i] = emb[(size_t)ids[row]*DM + c];
}

// ---------------- rmsnorm -> bf16 output (wave-shuffle reduce, 1 barrier) ----
__global__ __launch_bounds__(256) void rmsnorm_bf16_kernel(const float* __restrict__ x,
        const float* __restrict__ w, unsigned short* __restrict__ h){
    int row = blockIdx.x;
    const float* xr = x + (size_t)row*DM;
    __shared__ float red[4];
    int tid = threadIdx.x, lane = tid & 63, wv = tid >> 6;
    float s = 0.f;
    for (int c = tid; c < DM; c += 256){ float v = xr[c]; s += v*v; }
    #pragma unroll
    for (int o = 32; o > 0; o >>= 1) s += __shfl_xor(s, o, 64);
    if (lane == 0) red[wv] = s;
    __syncthreads();
    float tot = red[0] + red[1] + red[2] + red[3];
    float r = 1.0f / sqrtf(tot*(1.0f/DM) + 1e-5f);
    for (int c = tid; c < DM; c += 256) h[(size_t)row*DM + c] = f2bf(xr[c]*r*w[c]);
}

// ---------------- bf16 MFMA GEMM: C[M,N](f32) = A[M,K]bf16 * B[N,K]bf16^T ----
// Requires M%128==0, N%128==0, Kc%64==0. lda=ldb=K, ldc=N.
// 128x128 tile, BK=64, DOUBLE-BUFFERED global_load_lds prefetch pipeline:
// issue the next K-step's 8 loads before computing the current step, so the
// vmcnt drain at the single end-of-step __syncthreads overlaps with ds_read +
// 32 MFMA instead of stalling cold. XOR-swizzled LDS (read chunk ^= row&7,
// inverse pre-applied to the global source; staging dest stays linear as
// global_load_lds requires) keeps fragment reads conflict-free.
// Block mapping: flat id -> bijective XCD-chunk swizzle (m204) -> M-fastest.
// MODE: 0 = store, 1 = read-add-store, 2 = atomicAdd (split-K over blockIdx.z).
template<int MODE>
__global__ __launch_bounds__(256) void mfma_gemm_nt(const unsigned short* __restrict__ A,
        const unsigned short* __restrict__ B, float* __restrict__ C,
        int M, int N, int K, int Kc){
    __shared__ __align__(16) unsigned short Asm[2][128*64];
    __shared__ __align__(16) unsigned short Bsm[2][128*64];
    int tid = threadIdx.x;

    // ---- swizzled block mapping (x-y plane only; z = split-K chunk) ----
    int nwg  = gridDim.x * gridDim.y;
    int orig = blockIdx.y * gridDim.x + blockIdx.x;
    int q = nwg >> 3, r = nwg & 7;
    int xcd = orig & 7;
    int wg  = (xcd < r ? xcd*(q+1) : r*(q+1) + (xcd-r)*q) + (orig >> 3);
    int mb  = wg % gridDim.y;          // M fastest (gridDim.y = M/128)
    int nb  = wg / gridDim.y;
    int m0 = mb * 128, n0 = nb * 128;

    int lane = tid & 63;
    int quad = lane >> 4, l16 = lane & 15;
    int wave = tid >> 6;
    int wm = (wave >> 1) * 64, wn = (wave & 1) * 64;

    floatx4 acc[4][4] = {};

    // staging: round qr (0..3), chunk n = qr*256+tid; row = qr*32+(tid>>3),
    // dest chunk c = tid&7; source chunk = c ^ (row&7) = (tid&7)^((tid>>3)&7)
    int srow = tid >> 3;                                   // 0..31
    int csrc = ((tid & 7) ^ ((tid >> 3) & 7)) * 8;         // ushort offset
    const unsigned short* Ag = A + (size_t)(m0 + srow) * K + csrc;
    const unsigned short* Bg = B + (size_t)(n0 + srow) * K + csrc;

    int k0 = blockIdx.z * Kc;
    int nsteps = Kc >> 6;

    // prologue: stage step 0 into buffer 0
    #pragma unroll
    for (int qr = 0; qr < 4; qr++){
        GLL16(Ag + (size_t)qr*32*K + k0, &Asm[0][(qr*256 + tid)*8]);
        GLL16(Bg + (size_t)qr*32*K + k0, &Bsm[0][(qr*256 + tid)*8]);
    }
    __syncthreads();

    int cur = 0;
    for (int s = 0; s < nsteps; s++){
        // prefetch next step into the other buffer (issued BEFORE compute;
        // its completion is only waited at the end-of-step __syncthreads)
        if (s + 1 < nsteps){
            int kt = k0 + (s+1)*64;
            #pragma unroll
            for (int qr = 0; qr < 4; qr++){
                GLL16(Ag + (size_t)qr*32*K + kt, &Asm[cur^1][(qr*256 + tid)*8]);
                GLL16(Bg + (size_t)qr*32*K + kt, &Bsm[cur^1][(qr*256 + tid)*8]);
            }
        }

        #pragma unroll
        for (int ks = 0; ks < 2; ks++){
            bf16x8 af[4], bff[4];
            #pragma unroll
            for (int i = 0; i < 4; i++){
                int ar = wm + i*16 + l16;
                af[i]  = *(const bf16x8*)&Asm[cur][ar*64 + ((ks*4 + quad) ^ (ar & 7))*8];
                int br = wn + i*16 + l16;
                bff[i] = *(const bf16x8*)&Bsm[cur][br*64 + ((ks*4 + quad) ^ (br & 7))*8];
            }
            #pragma unroll
            for (int i = 0; i < 4; i++)
                #pragma unroll
                for (int j = 0; j < 4; j++)
                    acc[i][j] = __builtin_amdgcn_mfma_f32_16x16x32_bf16(af[i], bff[j], acc[i][j], 0, 0, 0);
        }
        __syncthreads();   // drains prefetch (had full compute phase to land)
        cur ^= 1;
    }

    // C/D layout: col = lane&15, row = quad*4 + reg   [m89-verified mapping]
    #pragma unroll
    for (int i = 0; i < 4; i++){
        int gm = m0 + wm + i*16 + quad*4;
        #pragma unroll
        for (int j = 0; j < 4; j++){
            int gn = n0 + wn + j*16 + l16;
            float* cp = C + (size_t)gm*N + gn;
            #pragma unroll
            for (int rr = 0; rr < 4; rr++){
                float v = acc[i][j][rr];
                if (MODE == 2){
                    atomicAdd(&cp[(size_t)rr*N], v);
                } else {
                    if (MODE == 1) v += cp[(size_t)rr*N];
                    cp[(size_t)rr*N] = v;
                }
            }
        }
    }
}

// ---------------- fp32 tiled GEMM (small shapes): C = A * Bw^T ----------------
__global__ __launch_bounds__(256) void gemm_nt(const float* __restrict__ A,
        const float* __restrict__ Bw, float* __restrict__ C, const float* __restrict__ bias,
        int M, int N, int K, int lda, int ldb, int ldc, int act, int accum){
    __shared__ float As[16][68];
    __shared__ float Bs[16][68];
    int tid = threadIdx.x;
    int tn = tid & 15, tm = tid >> 4;
    int n0 = blockIdx.x * 64, m0 = blockIdx.y * 64;
    float acc[4][4] = {{0.f}};
    for (int kt = 0; kt < K; kt += 16){
        int gk = kt + tn;
        bool kok = gk < K;
        #pragma unroll
        for (int r = 0; r < 4; r++){
            int m = tm + r*16;
            As[tn][m] = (kok && (m0 + m) < M) ? A[(size_t)(m0+m)*lda + gk] : 0.f;
            Bs[tn][m] = (kok && (n0 + m) < N) ? Bw[(size_t)(n0+m)*ldb + gk] : 0.f;
        }
        __syncthreads();
        #pragma unroll
        for (int kk = 0; kk < 16; kk++){
            float a0 = As[kk][tm*4+0], a1 = As[kk][tm*4+1], a2 = As[kk][tm*4+2], a3 = As[kk][tm*4+3];
            float b0 = Bs[kk][tn*4+0], b1 = Bs[kk][tn*4+1], b2 = Bs[kk][tn*4+2], b3 = Bs[kk][tn*4+3];
            acc[0][0] += a0*b0; acc[0][1] += a0*b1; acc[0][2] += a0*b2; acc[0][3] += a0*b3;
            acc[1][0] += a1*b0; acc[1][1] += a1*b1; acc[1][2] += a1*b2; acc[1][3] += a1*b3;
            acc[2][0] += a2*b0; acc[2][1] += a2*b1; acc[2][2] += a2*b2; acc[2][3] += a2*b3;
            acc[3][0] += a3*b0; acc[3][1] += a3*b1; acc[3][2] += a3*b2; acc[3][3] += a3*b3;
        }
        __syncthreads();
    }
    #pragma unroll
    for (int i = 0; i < 4; i++){
        int gm = m0 + tm*4 + i;
        if (gm >= M) continue;
        #pragma unroll
        for (int j = 0; j < 4; j++){
            int gn = n0 + tn*4 + j;
            if (gn >= N) continue;
            float v = acc[i][j];
            if (bias) v += bias[gn];
            if (act == 1) v = softplusf(v);
            size_t ci = (size_t)gm*ldc + gn;
            if (accum) v += C[ci];
            C[ci] = v;
        }
    }
}

// ---------------- depthwise causal conv (k=4) + bias + silu, f32 + bf16 out --
__global__ __launch_bounds__(256) void conv_silu_kernel(const float* __restrict__ xz,
        const float* __restrict__ cw, const float* __restrict__ cb,
        float* __restrict__ xs, unsigned short* __restrict__ xs_bf){
    int i = blockIdx.x*256 + threadIdx.x;
    if (i >= NBL*DI) return;
    int bl = i / DI, d = i - bl*DI;
    int l = bl & (NL-1);
    float acc = cb[d];
    #pragma unroll
    for (int j = 0; j < 4; j++){
        int off = j - 3;
        if (l + off >= 0) acc += cw[d*4+j] * xz[(size_t)(bl + off)*(2*DI) + d];
    }
    float v = siluf(acc);
    xs[i] = v;
    xs_bf[i] = f2bf(v);
}

// ---------------- transpose: out[C,R] = in[R,C]^T (in has leading dim ldin) --
__global__ __launch_bounds__(256) void transpose_kernel(const float* __restrict__ in,
        float* __restrict__ out, int R, int Ccols, int ldin){
    __shared__ float tile[32][33];
    int c0 = blockIdx.x*32, r0 = blockIdx.y*32;
    int tx = threadIdx.x & 31, ty = threadIdx.x >> 5;
    #pragma unroll
    for (int i = 0; i < 32; i += 8){
        int r = r0 + ty + i, c = c0 + tx;
        tile[ty+i][tx] = (r < R && c < Ccols) ? in[(size_t)r*ldin + c] : 0.f;
    }
    __syncthreads();
    #pragma unroll
    for (int i = 0; i < 32; i += 8){
        int r = r0 + tx, c = c0 + ty + i;
        if (c < Ccols && r < R) out[(size_t)c*R + r] = tile[tx][ty+i];
    }
}

// ---------------- fused double transpose: NBL x DI -> DI x NBL, two arrays ---
__global__ __launch_bounds__(256) void transpose2_kernel(const float* __restrict__ in1,
        float* __restrict__ out1, const float* __restrict__ in2, float* __restrict__ out2){
    __shared__ float tile[32][33];
    int c0 = blockIdx.x*32, r0 = blockIdx.y*32;   // c over DI, r over NBL
    int tx = threadIdx.x & 31, ty = threadIdx.x >> 5;
    #pragma unroll
    for (int i = 0; i < 32; i += 8)
        tile[ty+i][tx] = in1[(size_t)(r0+ty+i)*DI + (c0+tx)];
    __syncthreads();
    #pragma unroll
    for (int i = 0; i < 32; i += 8)
        out1[(size_t)(c0+ty+i)*NBL + (r0+tx)] = tile[tx][ty+i];
    __syncthreads();
    #pragma unroll
    for (int i = 0; i < 32; i += 8)
        tile[ty+i][tx] = in2[(size_t)(r0+ty+i)*DI + (c0+tx)];
    __syncthreads();
    #pragma unroll
    for (int i = 0; i < 32; i += 8)
        out2[(size_t)(c0+ty+i)*NBL + (r0+tx)] = tile[tx][ty+i];
}

// ---------------- wave-inclusive prefix scan (64 lanes, no barriers) ---------
static __device__ __forceinline__ float wave_incl_scan(float v, int lane){
    #pragma unroll
    for (int s = 1; s < 64; s <<= 1){
        float t = __shfl_up(v, s, 64);
        if (lane >= s) v += t;
    }
    return v;
}

// ---------------- selective scan (reference numerics) ----------------
// One WAVE per (b,d) row: 16 elements/lane, pure shuffle scans, zero barriers.
// y_t may alias dt_t (per-wave row exclusivity; reads precede writes).
__global__ __launch_bounds__(256) void scan_kernel(const float* __restrict__ u_t,
        const float* dt_t, const float* __restrict__ xdbl_t,
        const float* __restrict__ A_log, const float* __restrict__ Dp,
        float* y_t){
    int tid = threadIdx.x, lane = tid & 63, w = tid >> 6;
    int bd = blockIdx.x*4 + w;
    int b = bd / DI, d = bd - b*DI;
    size_t rowoff = (size_t)d*NBL + b*NL;
    int l0 = lane*16;

    float d16[16], u16[16];
    #pragma unroll
    for (int q = 0; q < 4; q++){
        float4 v = ((const float4*)(dt_t + rowoff + l0))[q];
        d16[q*4+0]=v.x; d16[q*4+1]=v.y; d16[q*4+2]=v.z; d16[q*4+3]=v.w;
        float4 u = ((const float4*)(u_t + rowoff + l0))[q];
        u16[q*4+0]=u.x; u16[q*4+1]=u.y; u16[q*4+2]=u.z; u16[q*4+3]=u.w;
    }
    float pl[16], yac[16];
    float run = 0.f;
    #pragma unroll
    for (int r = 0; r < 16; r++){ run += d16[r]; pl[r] = run; yac[r] = 0.f; }
    float inc = wave_incl_scan(run, lane);
    float ex  = inc - run;
    float T   = __shfl(inc, 63, 64);
    #pragma unroll
    for (int r = 0; r < 16; r++) pl[r] += ex;

    for (int n = 0; n < DS; n++){
        float An = -expf(A_log[d*DS + n]);
        float Bv[16], Cv[16];
        #pragma unroll
        for (int q = 0; q < 4; q++){
            float4 bv = ((const float4*)(xdbl_t + (size_t)(DTR+n)*NBL + b*NL + l0))[q];
            Bv[q*4+0]=bv.x; Bv[q*4+1]=bv.y; Bv[q*4+2]=bv.z; Bv[q*4+3]=bv.w;
            float4 cv = ((const float4*)(xdbl_t + (size_t)(DTR+DS+n)*NBL + b*NL + l0))[q];
            Cv[q*4+0]=cv.x; Cv[q*4+1]=cv.y; Cv[q*4+2]=cv.z; Cv[q*4+3]=cv.w;
        }
        float e[16], zl[16];
        float zrun = 0.f;
        #pragma unroll
        for (int r = 0; r < 16; r++){
            e[r] = expf(An * (T - pl[r]));
            zrun += d16[r]*u16[r]*Bv[r]*e[r];
            zl[r] = zrun;
        }
        float zinc = wave_incl_scan(zrun, lane);
        float zex  = zinc - zrun;
        #pragma unroll
        for (int r = 0; r < 16; r++){
            float num = zex + zl[r];
            yac[r] += num / (e[r] + 1e-12f) * Cv[r];
        }
    }
    float Dv = Dp[d];
    #pragma unroll
    for (int q = 0; q < 4; q++){
        float4 yo;
        yo.x = yac[q*4+0] + u16[q*4+0]*Dv;
        yo.y = yac[q*4+1] + u16[q*4+1]*Dv;
        yo.z = yac[q*4+2] + u16[q*4+2]*Dv;
        yo.w = yac[q*4+3] + u16[q*4+3]*Dv;
        ((float4*)(y_t + rowoff + l0))[q] = yo;
    }
}

// ---------------- transpose y back + gate with silu(res), bf16 output --------
__global__ __launch_bounds__(256) void gate_transpose_kernel(const float* __restrict__ y_t,
        const float* __restrict__ xz, unsigned short* __restrict__ ys){
    __shared__ float tile[32][33];
    int c0 = blockIdx.x*32;   // bl tile
    int r0 = blockIdx.y*32;   // d tile
    int tx = threadIdx.x & 31, ty = threadIdx.x >> 5;
    #pragma unroll
    for (int i = 0; i < 32; i += 8)
        tile[ty+i][tx] = y_t[(size_t)(r0+ty+i)*NBL + (c0+tx)];
    __syncthreads();
    #pragma unroll
    for (int i = 0; i < 32; i += 8){
        int d  = r0 + tx;
        int bl = c0 + ty + i;
        float g = siluf(xz[(size_t)bl*(2*DI) + DI + d]);
        ys[(size_t)bl*DI + d] = f2bf(tile[tx][ty+i] * g);
    }
}

extern "C" void kernel_launch(void* const* d_in, const int* in_sizes, int n_in,
                              void* d_out, int out_size, void* d_ws, size_t ws_size,
                              hipStream_t stream){
    const int*   ids    = (const int*)d_in[0];
    const float* emb    = (const float*)d_in[1];
    const float* W_in   = (const float*)d_in[2];
    const float* convw  = (const float*)d_in[3];
    const float* convb  = (const float*)d_in[4];
    const float* xproj  = (const float*)d_in[5];
    const float* dtw    = (const float*)d_in[6];
    const float* dtbias = (const float*)d_in[7];
    const float* Alog   = (const float*)d_in[8];
    const float* Dpar   = (const float*)d_in[9];
    const float* Wout   = (const float*)d_in[10];
    const float* normw  = (const float*)d_in[11];
    const float* normf  = (const float*)d_in[12];
    float* out = (float*)d_out;

    // ---- workspace layout ----
    float* ws    = (float*)d_ws;
    float* x     = ws;                              // NBL*DM f32
    float* xz    = x     + (size_t)NBL*DM;          // NBL*2*DI f32
    float* xs    = xz    + (size_t)NBL*2*DI;        // NBL*DI f32
    float* xdbl  = xs    + (size_t)NBL*DI;          // NBL*XDL f32 (padded, 80 valid)
    float* xdblt = xdbl  + (size_t)NBL*XDL;         // 80*NBL f32
    float* dtb   = xdblt + (size_t)NBL*80;          // NBL*DI f32 (later: ys_bf as ushort)
    float* dtt   = dtb   + (size_t)NBL*DI;          // DI*NBL f32 (scan writes y here too)
    float* ut    = dtt   + (size_t)NBL*DI;          // DI*NBL f32
    unsigned short* h_bf   = (unsigned short*)(ut + (size_t)NBL*DI);   // NBL*DM
    unsigned short* emb_bf = h_bf    + (size_t)NBL*DM;                 // NVOC*DM
    unsigned short* win_bf = emb_bf  + (size_t)NVOC*DM;                // 2*2*DI*DM
    unsigned short* wout_bf= win_bf  + (size_t)2*2*DI*DM;              // 2*DM*DI
    unsigned short* xs_bf  = wout_bf + (size_t)2*DM*DI;                // NBL*DI
    unsigned short* xprojp = xs_bf   + (size_t)NBL*DI;                 // 2*128*1536 (zero-padded)
    unsigned short* ys_bf  = (unsigned short*)dtb;
    float* yt = dtt;   // alias: scan writes y over dt (row-exclusive, safe)

    // ---- weight / emb casts (every call; ws is re-poisoned by harness) ----
    cast_bf16_kernel<<<(NVOC*DM/4 + 255)/256, 256, 0, stream>>>(emb, emb_bf, NVOC*DM/4);
    cast_bf16_kernel<<<(2*2*DI*DM/4 + 255)/256, 256, 0, stream>>>(W_in, win_bf, 2*2*DI*DM/4);
    cast_bf16_kernel<<<(2*DM*DI/4 + 255)/256, 256, 0, stream>>>(Wout, wout_bf, 2*DM*DI/4);
    cast_pad_xproj_kernel<<<(2*128*1536/4 + 255)/256, 256, 0, stream>>>(xproj, xprojp);

    embed_kernel<<<(NBL*DM + 255)/256, 256, 0, stream>>>(ids, emb, x);

    for (int i = 0; i < 2; i++){
        rmsnorm_bf16_kernel<<<NBL, 256, 0, stream>>>(x, normw + i*DM, h_bf);
        // xz = h @ W_in^T   (2048 x 3072, K=768) — bf16 MFMA
        mfma_gemm_nt<0><<<dim3(3072/128, NBL/128, 1), 256, 0, stream>>>(
                h_bf, win_bf + (size_t)i*2*DI*DM, xz, NBL, 2*DI, DM, DM);
        conv_silu_kernel<<<(NBL*DI + 255)/256, 256, 0, stream>>>(xz, convw + i*DI*4, convb + i*DI, xs, xs_bf);
        // xdbl = xs @ x_proj^T   (2048 x 80->128pad, K=1536) — bf16 MFMA split-K
        zero_f32_kernel<<<(NBL*XDL/4 + 255)/256, 256, 0, stream>>>(xdbl, NBL*XDL/4);
        mfma_gemm_nt<2><<<dim3(1, NBL/128, 8), 256, 0, stream>>>(
                xs_bf, xprojp + (size_t)i*128*DI, xdbl, NBL, XDL, DI, DI/8);
        // dt = softplus(xdbl[:, :48] @ dt_proj^T + bias)   (2048 x 1536, K=48) — fp32
        gemm_nt<<<dim3(24,32), 256, 0, stream>>>(xdbl, dtw + (size_t)i*DI*DTR, dtb, dtbias + i*DI,
                NBL, DI, DTR, XDL, DTR, DI, 1, 0);
        transpose_kernel<<<dim3(3,64),  256, 0, stream>>>(xdbl, xdblt, NBL, 80, XDL);
        transpose2_kernel<<<dim3(48,64), 256, 0, stream>>>(dtb, dtt, xs, ut);
        scan_kernel<<<NB*DI/4, 256, 0, stream>>>(ut, dtt, xdblt,
                Alog + (size_t)i*DI*DS, Dpar + i*DI, yt);
        gate_transpose_kernel<<<dim3(64,48), 256, 0, stream>>>(yt, xz, ys_bf);
        // x += ys @ W_out^T   (2048 x 768, K=1536) — bf16 MFMA split-K, atomic
        mfma_gemm_nt<2><<<dim3(DM/128, NBL/128, 2), 256, 0, stream>>>(
                ys_bf, wout_bf + (size_t)i*DM*DI, x, NBL, DM, DI, DI/2);
    }

    rmsnorm_bf16_kernel<<<NBL, 256, 0, stream>>>(x, normf, h_bf);
    // logits = h @ emb^T   (2048 x 32000, K=768) — bf16 MFMA
    mfma_gemm_nt<0><<<dim3(NVOC/128, NBL/128, 1), 256, 0, stream>>>(
            h_bf, emb_bf, out, NBL, NVOC, DM, DM);
}